// Round 1
// baseline (917.952 us; speedup 1.0000x reference)
//
#include <hip/hip_runtime.h>

#define LN_EPS 1e-5f

constexpr int BS = 32, LA = 300, LB = 1024, H = 512;
constexpr long RTOT = (long)H * H;  // 262144 rows of W (row r = k*512 + d)

// ws layout (floats):
//   [0, 131072)              bmean partials [32][8][512]
//   [131072, 147456)         bmean [32][512]
//   [147456, 147456+8388608) t [32][512][512]   (t[b,k,d])
// total ~32.6 MiB

// ---------------- kernel 1a: partial sums of feat_b over len_b ----------------
__global__ __launch_bounds__(512) void k_bmean_part(const float* __restrict__ fb,
                                                    float* __restrict__ part) {
  const int b = blockIdx.x >> 3, c = blockIdx.x & 7;
  const int e = threadIdx.x;
  const float* src = fb + ((long)b * LB + (long)c * 128) * H + e;
  float s = 0.f;
#pragma unroll 8
  for (int j = 0; j < 128; ++j) s += src[(long)j * H];
  part[((b << 3) + c) * H + e] = s;
}

// ---------------- kernel 1b: reduce partials -> bmean ----------------
__global__ __launch_bounds__(512) void k_bmean_final(const float* __restrict__ part,
                                                     float* __restrict__ bm) {
  const int b = blockIdx.x, e = threadIdx.x;
  float s = 0.f;
#pragma unroll
  for (int c = 0; c < 8; ++c) s += part[((b << 3) + c) * H + e];
  bm[b * H + e] = s * (1.f / LB);
}

// ---------------- kernel 2: t[b, r] = dot(W[r, :], bmean[b, :]) ----------------
// Memory-bound on W (536 MB). Block: 128 W-rows x all 32 batches, K-chunked by 32.
constexpr int K2_RT = 128, K2_KC = 32, K2_SW = 36;  // SW=36 keeps rows 16B-aligned, breaks stride-32 banks
__global__ __launch_bounds__(256) void k_wt(const float* __restrict__ W,
                                            const float* __restrict__ bm,
                                            float* __restrict__ t) {
  __shared__ float Wl[K2_RT * K2_SW];  // 18 KB
  __shared__ float Bl[BS * K2_KC];     // 4 KB
  const int tid = threadIdx.x;
  const int rowg = tid & 31;   // W-row group: rows rowg + 32*i
  const int bg = tid >> 5;     // batch group: b = bg*4 + j
  const long r0 = (long)blockIdx.x * K2_RT;
  float acc[4][4] = {};

  for (int e0 = 0; e0 < H; e0 += K2_KC) {
    // stage bmean chunk [32][32]
    {
      const int brow = tid >> 3, c4 = (tid & 7) << 2;
      const float4 v = *(const float4*)&bm[brow * H + e0 + c4];
      *(float4*)&Bl[brow * K2_KC + c4] = v;
    }
    // stage W tile: 128 rows x 32 cols (coalesced float4)
#pragma unroll
    for (int p = 0; p < 4; ++p) {
      const int f4 = tid + (p << 8);
      const int row = f4 >> 3, c4 = (f4 & 7) << 2;
      const float4 v = *(const float4*)&W[(r0 + row) * H + e0 + c4];
      *(float4*)&Wl[row * K2_SW + c4] = v;
    }
    __syncthreads();
#pragma unroll
    for (int kk = 0; kk < K2_KC; kk += 4) {
      float4 bmv[4];
#pragma unroll
      for (int j = 0; j < 4; ++j)
        bmv[j] = *(const float4*)&Bl[((bg << 2) + j) * K2_KC + kk];
#pragma unroll
      for (int i = 0; i < 4; ++i) {
        const float4 w = *(const float4*)&Wl[(rowg + (i << 5)) * K2_SW + kk];
#pragma unroll
        for (int j = 0; j < 4; ++j)
          acc[i][j] += w.x * bmv[j].x + w.y * bmv[j].y + w.z * bmv[j].z + w.w * bmv[j].w;
      }
    }
    __syncthreads();
  }
  // store t[b][r0 + rowg + 32*i]  (lanes consecutive in rowg -> coalesced)
#pragma unroll
  for (int j = 0; j < 4; ++j) {
    float* tb = t + ((long)((bg << 2) + j)) * RTOT + r0;
#pragma unroll
    for (int i = 0; i < 4; ++i) tb[rowg + (i << 5)] = acc[i][j];
  }
}

// ---------------- kernel 3: fused[b,a,k] = sum_d feat_a[b,a,d] * t[b,k,d] ----------------
// 64x64 tile per block, K-chunked by 32; result written to d_out (bias/LN applied later).
constexpr int K3_SW = 36;
__global__ __launch_bounds__(256) void k_fused(const float* __restrict__ fa,
                                               const float* __restrict__ t,
                                               float* __restrict__ out) {
  __shared__ float Al[64 * K3_SW];
  __shared__ float Tl[64 * K3_SW];
  const int tid = threadIdx.x;
  const int k0 = blockIdx.x * 64, a0 = blockIdx.y * 64, b = blockIdx.z;
  const int ar = tid >> 4;  // a = a0 + ar + 16*i
  const int kc = tid & 15;  // k = k0 + kc + 16*j
  float acc[4][4] = {};
  const float* Ab = fa + (long)b * LA * H;
  const float* Tb = t + (long)b * RTOT + (long)k0 * H;

  for (int d0 = 0; d0 < H; d0 += 32) {
#pragma unroll
    for (int p = 0; p < 2; ++p) {
      const int f4 = tid + (p << 8);
      const int row = f4 >> 3, c4 = (f4 & 7) << 2;
      const int a = a0 + row;
      float4 av = make_float4(0.f, 0.f, 0.f, 0.f);
      if (a < LA) av = *(const float4*)&Ab[(long)a * H + d0 + c4];
      *(float4*)&Al[row * K3_SW + c4] = av;
      const float4 tv = *(const float4*)&Tb[(long)row * H + d0 + c4];
      *(float4*)&Tl[row * K3_SW + c4] = tv;
    }
    __syncthreads();
#pragma unroll
    for (int kk = 0; kk < 32; kk += 4) {
      float4 a4[4], t4[4];
#pragma unroll
      for (int i = 0; i < 4; ++i) a4[i] = *(const float4*)&Al[(ar + (i << 4)) * K3_SW + kk];
#pragma unroll
      for (int j = 0; j < 4; ++j) t4[j] = *(const float4*)&Tl[(kc + (j << 4)) * K3_SW + kk];
#pragma unroll
      for (int i = 0; i < 4; ++i)
#pragma unroll
        for (int j = 0; j < 4; ++j)
          acc[i][j] += a4[i].x * t4[j].x + a4[i].y * t4[j].y + a4[i].z * t4[j].z + a4[i].w * t4[j].w;
    }
    __syncthreads();
  }
#pragma unroll
  for (int i = 0; i < 4; ++i) {
    const int a = a0 + ar + (i << 4);
    if (a < LA) {
      float* orow = out + ((long)b * LA + a) * H + k0;
#pragma unroll
      for (int j = 0; j < 4; ++j) orow[kc + (j << 4)] = acc[i][j];
    }
  }
}

// ---------------- kernel 4: x = fused + bias + feat_a; LayerNorm; in-place on d_out ----------------
__global__ __launch_bounds__(64) void k_ln(const float* __restrict__ fa,
                                           const float* __restrict__ bias,
                                           const float* __restrict__ gamma,
                                           const float* __restrict__ beta,
                                           float* __restrict__ out) {
  const long row = blockIdx.x;  // b*300 + a
  const int tid = threadIdx.x;
  float* fr = out + row * H;
  const float* ar = fa + row * H;
  float x[8];
  float s = 0.f, ss = 0.f;
#pragma unroll
  for (int q = 0; q < 2; ++q) {
    const int k = (q << 8) + (tid << 2);
    const float4 f = *(const float4*)&fr[k];
    const float4 a = *(const float4*)&ar[k];
    const float4 bi = *(const float4*)&bias[k];
    x[q * 4 + 0] = f.x + a.x + bi.x;
    x[q * 4 + 1] = f.y + a.y + bi.y;
    x[q * 4 + 2] = f.z + a.z + bi.z;
    x[q * 4 + 3] = f.w + a.w + bi.w;
#pragma unroll
    for (int u = 0; u < 4; ++u) { s += x[q * 4 + u]; ss += x[q * 4 + u] * x[q * 4 + u]; }
  }
#pragma unroll
  for (int o = 32; o; o >>= 1) { s += __shfl_xor(s, o); ss += __shfl_xor(ss, o); }
  const float mu = s * (1.f / H);
  const float var = ss * (1.f / H) - mu * mu;
  const float rs = rsqrtf(var + LN_EPS);
#pragma unroll
  for (int q = 0; q < 2; ++q) {
    const int k = (q << 8) + (tid << 2);
    const float4 g = *(const float4*)&gamma[k];
    const float4 be = *(const float4*)&beta[k];
    float4 o;
    o.x = (x[q * 4 + 0] - mu) * rs * g.x + be.x;
    o.y = (x[q * 4 + 1] - mu) * rs * g.y + be.y;
    o.z = (x[q * 4 + 2] - mu) * rs * g.z + be.z;
    o.w = (x[q * 4 + 3] - mu) * rs * g.w + be.w;
    *(float4*)&fr[k] = o;
  }
}

extern "C" void kernel_launch(void* const* d_in, const int* in_sizes, int n_in,
                              void* d_out, int out_size, void* d_ws, size_t ws_size,
                              hipStream_t stream) {
  const float* fa = (const float*)d_in[0];
  const float* fb = (const float*)d_in[1];
  const float* W = (const float*)d_in[2];
  const float* bias = (const float*)d_in[3];
  const float* gamma = (const float*)d_in[4];
  const float* beta = (const float*)d_in[5];
  float* out = (float*)d_out;
  float* ws = (float*)d_ws;
  float* part = ws;
  float* bm = ws + 131072;
  float* t = ws + 147456;

  hipLaunchKernelGGL(k_bmean_part, dim3(256), dim3(512), 0, stream, fb, part);
  hipLaunchKernelGGL(k_bmean_final, dim3(32), dim3(512), 0, stream, part, bm);
  hipLaunchKernelGGL(k_wt, dim3((int)(RTOT / K2_RT)), dim3(256), 0, stream, W, bm, t);
  hipLaunchKernelGGL(k_fused, dim3(8, 5, 32), dim3(256), 0, stream, fa, t, out);
  hipLaunchKernelGGL(k_ln, dim3(BS * LA), dim3(64), 0, stream, fa, bias, gamma, beta, out);
}

// Round 3
// 836.424 us; speedup vs baseline: 1.0975x; 1.0975x over previous
//
#include <hip/hip_runtime.h>

#define LN_EPS 1e-5f

typedef short s8v __attribute__((ext_vector_type(8)));
typedef float f4v __attribute__((ext_vector_type(4)));

constexpr int BS = 32, LA = 300, LB = 1024, H = 512;
constexpr long RTOT = (long)H * H;  // 262144 W rows (r = k*512 + d)

// ws layout (bytes):
//   [0,       524288)   part  [32][8][512] fp32
//   [524288,  557056)   bmh   [32][512] bf16 (hi plane)
//   [557056,  589824)   bml   [32][512] bf16 (lo plane)
//   [589824,  +16MiB)   thi   [32][512][512] bf16 (hi plane)
//   [+16MiB,  +32MiB)   tlo   [32][512][512] bf16 (lo plane)

union U8 { s8v v; unsigned u[4]; };
union FU { float f; unsigned u; };

__device__ inline unsigned pack_hi16(unsigned a, unsigned b) {
  return (a >> 16) | (b & 0xffff0000u);  // elem0 = a.hi16 (low half), elem1 = b.hi16
}

// Split 8 fp32 into hi/lo bf16 (truncation split; lo compensates hi exactly).
__device__ inline void split8(const float4 w0, const float4 w1, s8v& hi, s8v& lo) {
  FU f[8] = {{w0.x}, {w0.y}, {w0.z}, {w0.w}, {w1.x}, {w1.y}, {w1.z}, {w1.w}};
  U8 h, l;
#pragma unroll
  for (int p = 0; p < 4; ++p) {
    const unsigned ua = f[2 * p].u, ub = f[2 * p + 1].u;
    h.u[p] = pack_hi16(ua, ub);
    FU ra, rb;
    ra.f = f[2 * p].f - __uint_as_float(ua & 0xffff0000u);
    rb.f = f[2 * p + 1].f - __uint_as_float(ub & 0xffff0000u);
    l.u[p] = pack_hi16(ra.u, rb.u);
  }
  hi = h.v;
  lo = l.v;
}

// ---------------- kernel 1a: partial sums of feat_b over len_b ----------------
__global__ __launch_bounds__(512) void k_bmean_part(const float* __restrict__ fb,
                                                    float* __restrict__ part) {
  const int b = blockIdx.x >> 3, c = blockIdx.x & 7;
  const int e = threadIdx.x;
  const float* src = fb + ((long)b * LB + (long)c * 128) * H + e;
  float s = 0.f;
#pragma unroll 8
  for (int j = 0; j < 128; ++j) s += src[(long)j * H];
  part[((b << 3) + c) * H + e] = s;
}

// ---------------- kernel 1b: reduce partials -> bm hi/lo bf16 planes ----------------
__global__ __launch_bounds__(512) void k_bmean_final(const float* __restrict__ part,
                                                     unsigned short* __restrict__ bmh,
                                                     unsigned short* __restrict__ bml) {
  const int b = blockIdx.x, e = threadIdx.x;
  float s = 0.f;
#pragma unroll
  for (int c = 0; c < 8; ++c) s += part[((b << 3) + c) * H + e];
  const float v = s * (1.f / LB);
  FU u; u.f = v;
  bmh[b * H + e] = (unsigned short)(u.u >> 16);
  FU r; r.f = v - __uint_as_float(u.u & 0xffff0000u);
  bml[b * H + e] = (unsigned short)(r.u >> 16);
}

// ---------------- kernel 2: t[b, r] = dot(W[r, :], bm[b, :]) via hi/lo bf16 MFMA ----------------
// No LDS: W fragments load directly from global (lane-contiguous 32 B), split in regs.
__global__ __launch_bounds__(256) void k_wt(const float* __restrict__ W,
                                            const unsigned short* __restrict__ bmh,
                                            const unsigned short* __restrict__ bml,
                                            unsigned short* __restrict__ thi,
                                            unsigned short* __restrict__ tlo) {
  const int tid = threadIdx.x, wv = tid >> 6, ln = tid & 63;
  const int l16 = ln & 15, kg = ln >> 4;
  const long r0 = (long)blockIdx.x * 256 + wv * 64;

  f4v acc[2][4];
#pragma unroll
  for (int m = 0; m < 2; ++m)
#pragma unroll
    for (int n = 0; n < 4; ++n) acc[m][n] = (f4v){0.f, 0.f, 0.f, 0.f};

  const float* wp = W + (r0 + l16) * (long)H + kg * 8;
  const int aoff = l16 * H + kg * 8;

  for (int e0 = 0; e0 < H; e0 += 32) {
    // A fragments (bm rows, hi/lo planes) — 64 KB total, L1/L2-hot
    const s8v ah0 = *(const s8v*)(bmh + aoff + e0);
    const s8v al0 = *(const s8v*)(bml + aoff + e0);
    const s8v ah1 = *(const s8v*)(bmh + 16 * H + aoff + e0);
    const s8v al1 = *(const s8v*)(bml + 16 * H + aoff + e0);
#pragma unroll
    for (int nt = 0; nt < 4; ++nt) {
      const float* p = wp + (long)nt * 16 * H + e0;
      const float4 w0 = *(const float4*)p;
      const float4 w1 = *(const float4*)(p + 4);
      s8v wh, wl;
      split8(w0, w1, wh, wl);
      // (hi*hi + lo*hi + hi*lo) — lo*lo dropped (~2^-32 rel)
      acc[0][nt] = __builtin_amdgcn_mfma_f32_16x16x32_bf16(ah0, wh, acc[0][nt], 0, 0, 0);
      acc[0][nt] = __builtin_amdgcn_mfma_f32_16x16x32_bf16(al0, wh, acc[0][nt], 0, 0, 0);
      acc[0][nt] = __builtin_amdgcn_mfma_f32_16x16x32_bf16(ah0, wl, acc[0][nt], 0, 0, 0);
      acc[1][nt] = __builtin_amdgcn_mfma_f32_16x16x32_bf16(ah1, wh, acc[1][nt], 0, 0, 0);
      acc[1][nt] = __builtin_amdgcn_mfma_f32_16x16x32_bf16(al1, wh, acc[1][nt], 0, 0, 0);
      acc[1][nt] = __builtin_amdgcn_mfma_f32_16x16x32_bf16(ah1, wl, acc[1][nt], 0, 0, 0);
    }
  }
  // D layout: row(m=batch) = kg*4 + j, col(n=W-row) = l16; store t split hi/lo
#pragma unroll
  for (int m = 0; m < 2; ++m)
#pragma unroll
    for (int nt = 0; nt < 4; ++nt)
#pragma unroll
      for (int j = 0; j < 4; ++j) {
        const float v = acc[m][nt][j];
        const long idx = (long)(m * 16 + kg * 4 + j) * RTOT + r0 + nt * 16 + l16;
        FU u; u.f = v;
        thi[idx] = (unsigned short)(u.u >> 16);
        FU r; r.f = v - __uint_as_float(u.u & 0xffff0000u);
        tlo[idx] = (unsigned short)(r.u >> 16);
      }
}

// ---------------- kernel 3: fused[b,a,k] = sum_d fa[b,a,d] * t[b,k,d] via hi/lo MFMA ----------------
// Block tile 64a x 128k (wave: 64a x 32k). A=fa split in regs, B=t hi/lo planes from global.
__global__ __launch_bounds__(256) void k_fused(const float* __restrict__ fa,
                                               const unsigned short* __restrict__ thi,
                                               const unsigned short* __restrict__ tlo,
                                               float* __restrict__ out) {
  const int tid = threadIdx.x, wv = tid >> 6, ln = tid & 63;
  const int l16 = ln & 15, kg = ln >> 4;
  const int b = blockIdx.z, a0 = blockIdx.y * 64, k0 = blockIdx.x * 128 + wv * 32;

  f4v acc[4][2];
#pragma unroll
  for (int m = 0; m < 4; ++m)
#pragma unroll
    for (int n = 0; n < 2; ++n) acc[m][n] = (f4v){0.f, 0.f, 0.f, 0.f};

  const float* fab = fa + (long)b * LA * H;
  const unsigned short* th = thi + (long)b * RTOT;
  const unsigned short* tl = tlo + (long)b * RTOT;

  for (int d0 = 0; d0 < H; d0 += 32) {
    s8v afh[4], afl[4];
#pragma unroll
    for (int mt = 0; mt < 4; ++mt) {
      int a = a0 + mt * 16 + l16;
      if (a > LA - 1) a = LA - 1;  // clamp; garbage rows discarded at store
      const float* p = fab + (long)a * H + d0 + kg * 8;
      const float4 w0 = *(const float4*)p;
      const float4 w1 = *(const float4*)(p + 4);
      split8(w0, w1, afh[mt], afl[mt]);
    }
#pragma unroll
    for (int nt = 0; nt < 2; ++nt) {
      const long boff = (long)(k0 + nt * 16 + l16) * H + d0 + kg * 8;
      const s8v bh = *(const s8v*)(th + boff);
      const s8v bl = *(const s8v*)(tl + boff);
#pragma unroll
      for (int mt = 0; mt < 4; ++mt) {
        acc[mt][nt] = __builtin_amdgcn_mfma_f32_16x16x32_bf16(afh[mt], bh, acc[mt][nt], 0, 0, 0);
        acc[mt][nt] = __builtin_amdgcn_mfma_f32_16x16x32_bf16(afl[mt], bh, acc[mt][nt], 0, 0, 0);
        acc[mt][nt] = __builtin_amdgcn_mfma_f32_16x16x32_bf16(afh[mt], bl, acc[mt][nt], 0, 0, 0);
      }
    }
  }
#pragma unroll
  for (int mt = 0; mt < 4; ++mt)
#pragma unroll
    for (int nt = 0; nt < 2; ++nt)
#pragma unroll
      for (int j = 0; j < 4; ++j) {
        const int a = a0 + mt * 16 + kg * 4 + j;
        if (a < LA)
          out[((long)b * LA + a) * H + k0 + nt * 16 + l16] = acc[mt][nt][j];
      }
}

// ---------------- kernel 4: x = fused + bias + feat_a; LayerNorm in-place on d_out ----------------
__global__ __launch_bounds__(64) void k_ln(const float* __restrict__ fa,
                                           const float* __restrict__ bias,
                                           const float* __restrict__ gamma,
                                           const float* __restrict__ beta,
                                           float* __restrict__ out) {
  const long row = blockIdx.x;  // b*300 + a
  const int tid = threadIdx.x;
  float* fr = out + row * H;
  const float* ar = fa + row * H;
  float x[8];
  float s = 0.f, ss = 0.f;
#pragma unroll
  for (int q = 0; q < 2; ++q) {
    const int k = (q << 8) + (tid << 2);
    const float4 f = *(const float4*)&fr[k];
    const float4 a = *(const float4*)&ar[k];
    const float4 bi = *(const float4*)&bias[k];
    x[q * 4 + 0] = f.x + a.x + bi.x;
    x[q * 4 + 1] = f.y + a.y + bi.y;
    x[q * 4 + 2] = f.z + a.z + bi.z;
    x[q * 4 + 3] = f.w + a.w + bi.w;
#pragma unroll
    for (int u = 0; u < 4; ++u) { s += x[q * 4 + u]; ss += x[q * 4 + u] * x[q * 4 + u]; }
  }
#pragma unroll
  for (int o = 32; o; o >>= 1) { s += __shfl_xor(s, o); ss += __shfl_xor(ss, o); }
  const float mu = s * (1.f / H);
  const float var = ss * (1.f / H) - mu * mu;
  const float rs = rsqrtf(var + LN_EPS);
#pragma unroll
  for (int q = 0; q < 2; ++q) {
    const int k = (q << 8) + (tid << 2);
    const float4 g = *(const float4*)&gamma[k];
    const float4 be = *(const float4*)&beta[k];
    float4 o;
    o.x = (x[q * 4 + 0] - mu) * rs * g.x + be.x;
    o.y = (x[q * 4 + 1] - mu) * rs * g.y + be.y;
    o.z = (x[q * 4 + 2] - mu) * rs * g.z + be.z;
    o.w = (x[q * 4 + 3] - mu) * rs * g.w + be.w;
    *(float4*)&fr[k] = o;
  }
}

extern "C" void kernel_launch(void* const* d_in, const int* in_sizes, int n_in,
                              void* d_out, int out_size, void* d_ws, size_t ws_size,
                              hipStream_t stream) {
  const float* fa = (const float*)d_in[0];
  const float* fb = (const float*)d_in[1];
  const float* W = (const float*)d_in[2];
  const float* bias = (const float*)d_in[3];
  const float* gamma = (const float*)d_in[4];
  const float* beta = (const float*)d_in[5];
  float* out = (float*)d_out;
  char* ws = (char*)d_ws;

  float* part = (float*)ws;
  unsigned short* bmh = (unsigned short*)(ws + 524288);
  unsigned short* bml = (unsigned short*)(ws + 557056);
  unsigned short* thi = (unsigned short*)(ws + 589824);
  unsigned short* tlo = (unsigned short*)(ws + 589824 + 16777216);

  hipLaunchKernelGGL(k_bmean_part, dim3(256), dim3(512), 0, stream, fb, part);
  hipLaunchKernelGGL(k_bmean_final, dim3(32), dim3(512), 0, stream, part, bmh, bml);
  hipLaunchKernelGGL(k_wt, dim3((int)(RTOT / 256)), dim3(256), 0, stream, W, bmh, bml, thi, tlo);
  hipLaunchKernelGGL(k_fused, dim3(4, 5, 32), dim3(256), 0, stream, fa, thi, tlo, out);
  hipLaunchKernelGGL(k_ln, dim3(BS * LA), dim3(64), 0, stream, fa, bias, gamma, beta, out);
}